// Round 3
// baseline (939.023 us; speedup 1.0000x reference)
//
#include <hip/hip_runtime.h>

#define N_NODES 100000
#define N_EDGES 1600000
#define N_FEAT  602
#define HIDDEN  128
#define N_CLS   41
#define Y2_STRIDE 48   // padded rows: 192B, cache-line aligned

typedef __attribute__((ext_vector_type(8))) short bf16x8;
typedef __attribute__((ext_vector_type(4))) float f32x4;

#define KPAD 608      // 19 * 32

// bf16 round-to-nearest-even, returns hi and residual
__device__ inline unsigned short bf_hi(float f, float& rem) {
    unsigned int u = __float_as_uint(f);
    unsigned int r = u + 0x7FFF + ((u >> 16) & 1);
    unsigned short h = (unsigned short)(r >> 16);
    rem = f - __uint_as_float((unsigned int)h << 16);
    return h;
}
__device__ inline unsigned short bf_rn(float f) {
    unsigned int u = __float_as_uint(f);
    unsigned int r = u + 0x7FFF + ((u >> 16) & 1);
    return (unsigned short)(r >> 16);
}

// ---------------- degrees ----------------
__global__ void k_deg(const int* __restrict__ src, const int* __restrict__ dst,
                      int* __restrict__ deg_out, int* __restrict__ deg_in) {
    int e = blockIdx.x * blockDim.x + threadIdx.x;
    if (e < N_EDGES) {
        atomicAdd(&deg_out[src[e]], 1);
        atomicAdd(&deg_in[dst[e]], 1);
    }
}

__global__ void k_norm(const int* __restrict__ deg_out, const int* __restrict__ deg_in,
                       float* __restrict__ ns, float* __restrict__ nd) {
    int i = blockIdx.x * blockDim.x + threadIdx.x;
    if (i < N_NODES) {
        ns[i] = 1.0f / sqrtf((float)max(deg_out[i], 1));
        nd[i] = 1.0f / sqrtf((float)max(deg_in[i], 1));
    }
}

// ---------------- W1 convert: fp32 [602][128] -> MFMA-fragment-ordered bf16 hi/lo ----------------
// Bpk[((kt*8 + ni)*16 + l16)*32 + quad*8 + e]  holds  W1^T[col = ni*16+l16][k = kt*32+quad*8+e].
// Per (kt,ni) a wave's fragment read is 1024 consecutive bytes -> fully coalesced L2 hits.
__global__ void k_wconv(const float* __restrict__ W1,
                        unsigned short* __restrict__ Bpk_hi,
                        unsigned short* __restrict__ Bpk_lo) {
    int c = blockIdx.x;     // col 0..127
    int k = threadIdx.x;    // 0..639
    if (k >= KPAD) return;
    float w = (k < N_FEAT) ? W1[(long)k * HIDDEN + c] : 0.f;
    float rem;
    unsigned short h = bf_hi(w, rem);
    unsigned short l = bf_rn(rem);
    int kt = k >> 5, kr = k & 31;
    int ni = c >> 4, l16 = c & 15;
    long idx = (((long)kt * 8 + ni) * 16 + l16) * 32 + kr;
    Bpk_hi[idx] = h;
    Bpk_lo[idx] = l;
}

// ---------------- exclusive scan of deg_in -> row_ptr ----------------
__global__ void k_scan1(const int* __restrict__ deg_in, int* __restrict__ row_ptr,
                        int* __restrict__ blk) {
    __shared__ int s[1024];
    int t = threadIdx.x;
    int i = blockIdx.x * 1024 + t;
    int v = (i < N_NODES) ? deg_in[i] : 0;
    s[t] = v; __syncthreads();
    for (int off = 1; off < 1024; off <<= 1) {
        int x = s[t];
        if (t >= off) x += s[t - off];
        __syncthreads();
        s[t] = x; __syncthreads();
    }
    if (i < N_NODES) row_ptr[i] = s[t] - v;
    if (t == 1023) blk[blockIdx.x] = s[1023];
}

__global__ void k_scan2(int* __restrict__ blk, int nblk) {
    __shared__ int s[128];
    int t = threadIdx.x;
    int v = (t < nblk) ? blk[t] : 0;
    s[t] = v; __syncthreads();
    for (int off = 1; off < 128; off <<= 1) {
        int x = s[t];
        if (t >= off) x += s[t - off];
        __syncthreads();
        s[t] = x; __syncthreads();
    }
    if (t < nblk) blk[t] = s[t] - v;
}

// also initializes cursor = row_ptr so k_fill needs no row_ptr gather
__global__ void k_scan3(int* __restrict__ row_ptr, const int* __restrict__ blk,
                        int* __restrict__ cursor) {
    int i = blockIdx.x * blockDim.x + threadIdx.x;
    if (i < N_NODES) {
        int v = row_ptr[i] + blk[i >> 10];
        row_ptr[i] = v;
        cursor[i] = v;
    }
}

// ---------------- CSR fill (bucket by dst); cursor pre-seeded with row_ptr ----------------
__global__ void k_fill(const int* __restrict__ src, const int* __restrict__ dst,
                       int* __restrict__ cursor, int* __restrict__ csr_src) {
    int e = blockIdx.x * blockDim.x + threadIdx.x;
    if (e < N_EDGES) {
        int p = atomicAdd(&cursor[dst[e]], 1);
        csr_src[p] = src[e];
    }
}

// ---------------- GEMM1 (split-bf16 MFMA, barrier-free) ----------------
// y1 = ns ⊙ (x @ W1). Block = 128 rows, 4 waves, wave owns 32 rows x 128 cols
// (acc 2x8 of 16x16). A: global -> registers directly as MFMA fragments, converted to
// bf16 hi/lo in-register, 1-tile-ahead prefetch. B: 311 KB total, L2-resident ->
// read fragments DIRECTLY from global in prepacked order (coalesced 1KB bursts).
// No LDS, no __syncthreads: waves free-run, latencies interleave across 12 waves/CU.
__global__ __launch_bounds__(256, 3) void k_gemm1(const float* __restrict__ x,
                                                  const unsigned short* __restrict__ Bpk_hi,
                                                  const unsigned short* __restrict__ Bpk_lo,
                                                  const float* __restrict__ ns,
                                                  float* __restrict__ y1) {
    int tid = threadIdx.x;
    int lane = tid & 63;
    int wave = tid >> 6;
    int quad = lane >> 4, l16 = lane & 15;
    int m0 = blockIdx.x * 128;

    f32x4 acc[2][8];
    #pragma unroll
    for (int i = 0; i < 2; i++)
        #pragma unroll
        for (int j = 0; j < 8; j++)
            acc[i][j] = (f32x4){0.f, 0.f, 0.f, 0.f};

    // A fragment rows for this lane (mi = 0,1), clamped for the last block
    long r0 = min(m0 + wave * 32 + l16,      N_NODES - 1);
    long r1 = min(m0 + wave * 32 + 16 + l16, N_NODES - 1);
    const float* xr0 = x + r0 * N_FEAT + quad * 8;
    const float* xr1 = x + r1 * N_FEAT + quad * 8;

    // per-lane B fragment base (shorts): within a (kt,ni) 4KB-chunk, lane reads l16*64B + quad*16B
    const unsigned short* bh_base = Bpk_hi + l16 * 32 + quad * 8;
    const unsigned short* bl_base = Bpk_lo + l16 * 32 + quad * 8;

    float4 c0, c1, c2, c3;   // current A regs: mi0 (c0,c1), mi1 (c2,c3)

    c0 = *(const float4*)(xr0);      c1 = *(const float4*)(xr0 + 4);
    c2 = *(const float4*)(xr1);      c3 = *(const float4*)(xr1 + 4);

    for (int kt = 0; kt < 19; ++kt) {
        // ---- prefetch NEXT tile's A (consumed one full tile later) ----
        float4 n0, n1, n2, n3;
        if (kt < 18) {
            const float* p0 = xr0 + (kt + 1) * 32;
            const float* p1 = xr1 + (kt + 1) * 32;
            n0 = *(const float4*)(p0);     n1 = *(const float4*)(p0 + 4);
            n2 = *(const float4*)(p1);     n3 = *(const float4*)(p1 + 4);
        }

        // ---- convert current A regs -> bf16 hi/lo fragments (in-register) ----
        if (kt == 18 && quad == 3) {
            // tile covers k = 576..607; zero k >= 602 (quad 3 holds k 600..607)
            c0.z = 0.f; c0.w = 0.f; c1 = make_float4(0.f, 0.f, 0.f, 0.f);
            c2.z = 0.f; c2.w = 0.f; c3 = make_float4(0.f, 0.f, 0.f, 0.f);
        }
        bf16x8 ah[2], al[2];
        {
            float rem;
            ah[0][0] = (short)bf_hi(c0.x, rem); al[0][0] = (short)bf_rn(rem);
            ah[0][1] = (short)bf_hi(c0.y, rem); al[0][1] = (short)bf_rn(rem);
            ah[0][2] = (short)bf_hi(c0.z, rem); al[0][2] = (short)bf_rn(rem);
            ah[0][3] = (short)bf_hi(c0.w, rem); al[0][3] = (short)bf_rn(rem);
            ah[0][4] = (short)bf_hi(c1.x, rem); al[0][4] = (short)bf_rn(rem);
            ah[0][5] = (short)bf_hi(c1.y, rem); al[0][5] = (short)bf_rn(rem);
            ah[0][6] = (short)bf_hi(c1.z, rem); al[0][6] = (short)bf_rn(rem);
            ah[0][7] = (short)bf_hi(c1.w, rem); al[0][7] = (short)bf_rn(rem);
            ah[1][0] = (short)bf_hi(c2.x, rem); al[1][0] = (short)bf_rn(rem);
            ah[1][1] = (short)bf_hi(c2.y, rem); al[1][1] = (short)bf_rn(rem);
            ah[1][2] = (short)bf_hi(c2.z, rem); al[1][2] = (short)bf_rn(rem);
            ah[1][3] = (short)bf_hi(c2.w, rem); al[1][3] = (short)bf_rn(rem);
            ah[1][4] = (short)bf_hi(c3.x, rem); al[1][4] = (short)bf_rn(rem);
            ah[1][5] = (short)bf_hi(c3.y, rem); al[1][5] = (short)bf_rn(rem);
            ah[1][6] = (short)bf_hi(c3.z, rem); al[1][6] = (short)bf_rn(rem);
            ah[1][7] = (short)bf_hi(c3.w, rem); al[1][7] = (short)bf_rn(rem);
        }

        // ---- B fragments straight from L2 (prepacked, coalesced) + MFMA ----
        const unsigned short* bh = bh_base + (long)kt * 4096;
        const unsigned short* bl = bl_base + (long)kt * 4096;
        #pragma unroll
        for (int ni = 0; ni < 8; ++ni) {
            bf16x8 vh = *(const bf16x8*)(bh + ni * 512);
            bf16x8 vl = *(const bf16x8*)(bl + ni * 512);
            #pragma unroll
            for (int mi = 0; mi < 2; ++mi) {
                acc[mi][ni] = __builtin_amdgcn_mfma_f32_16x16x32_bf16(ah[mi], vh, acc[mi][ni], 0, 0, 0);
                acc[mi][ni] = __builtin_amdgcn_mfma_f32_16x16x32_bf16(al[mi], vh, acc[mi][ni], 0, 0, 0);
                acc[mi][ni] = __builtin_amdgcn_mfma_f32_16x16x32_bf16(ah[mi], vl, acc[mi][ni], 0, 0, 0);
            }
        }

        if (kt < 18) { c0 = n0; c1 = n1; c2 = n2; c3 = n3; }
    }

    // epilogue: C/D layout col = lane&15, row = quad*4 + r
    #pragma unroll
    for (int mi = 0; mi < 2; ++mi) {
        #pragma unroll
        for (int r = 0; r < 4; ++r) {
            int row = m0 + wave * 32 + mi * 16 + quad * 4 + r;
            if (row < N_NODES) {
                float s = ns[row];
                #pragma unroll
                for (int ni = 0; ni < 8; ++ni) {
                    int col = ni * 16 + l16;
                    y1[(long)row * HIDDEN + col] = acc[mi][ni][r] * s;
                }
            }
        }
    }
}

// ---------------- SpMM1 + epilogue: h1 = relu(A@y1 * nd + b1) ----------------
// unroll x8 with independent accumulators -> 8 row-gathers (4 KB) in flight per wave
__global__ __launch_bounds__(256) void k_spmm1(const float* __restrict__ y1,
                                               const int* __restrict__ row_ptr,
                                               const int* __restrict__ deg_in,
                                               const int* __restrict__ csr_src,
                                               const float* __restrict__ nd,
                                               const float* __restrict__ b1,
                                               float* __restrict__ h1) {
    int wave = threadIdx.x >> 6, lane = threadIdx.x & 63;
    int n = blockIdx.x * 4 + wave;
    if (n >= N_NODES) return;
    int base = row_ptr[n], deg = deg_in[n];
    const float2* yp = (const float2*)y1;
    float ax[8], ay[8];
    #pragma unroll
    for (int u = 0; u < 8; ++u) { ax[u] = 0.f; ay[u] = 0.f; }
    int j = 0;
    for (; j + 8 <= deg; j += 8) {
        int s[8];
        #pragma unroll
        for (int u = 0; u < 8; ++u) s[u] = csr_src[base + j + u];
        #pragma unroll
        for (int u = 0; u < 8; ++u) {
            float2 v = yp[(long)s[u] * 64 + lane];
            ax[u] += v.x; ay[u] += v.y;
        }
    }
    for (; j < deg; ++j) {
        int s = csr_src[base + j];
        float2 v = yp[(long)s * 64 + lane];
        ax[0] += v.x; ay[0] += v.y;
    }
    float a0 = ((ax[0] + ax[1]) + (ax[2] + ax[3])) + ((ax[4] + ax[5]) + (ax[6] + ax[7]));
    float a1 = ((ay[0] + ay[1]) + (ay[2] + ay[3])) + ((ay[4] + ay[5]) + (ay[6] + ay[7]));
    float d = nd[n];
    float2 b = ((const float2*)b1)[lane];
    float2 r;
    r.x = fmaxf(a0 * d + b.x, 0.f);
    r.y = fmaxf(a1 * d + b.y, 0.f);
    ((float2*)(h1 + (long)n * HIDDEN))[lane] = r;
}

// ---------------- GEMM2: y2 = ns ⊙ (h1 @ W2), padded rows (stride 48) ----------------
__global__ __launch_bounds__(256) void k_gemm2(const float* __restrict__ h1,
                                               const float* __restrict__ W2,
                                               const float* __restrict__ ns,
                                               float* __restrict__ y2) {
    __shared__ float sz[64 * 132];
    __shared__ float sw[128 * 44];
    int tid = threadIdx.x;
    int m0 = blockIdx.x * 64;
    for (int idx = tid; idx < 128 * 44; idx += 256) {
        int k = idx / 44, c = idx % 44;
        sw[idx] = (c < N_CLS) ? W2[k * N_CLS + c] : 0.f;
    }
    for (int idx = tid; idx < 64 * 32; idx += 256) {
        int r = idx >> 5, q = idx & 31;
        int row = m0 + r;
        float4 v = make_float4(0.f, 0.f, 0.f, 0.f);
        if (row < N_NODES) v = ((const float4*)h1)[(long)row * 32 + q];
        *((float4*)&sz[r * 132 + q * 4]) = v;
    }
    __syncthreads();
    int r = tid >> 2, cq = tid & 3;
    int c0 = cq * 11;
    float acc[11];
    #pragma unroll
    for (int j = 0; j < 11; j++) acc[j] = 0.f;
    #pragma unroll 8
    for (int k = 0; k < 128; ++k) {
        float a = sz[r * 132 + k];
        #pragma unroll
        for (int j = 0; j < 11; j++) acc[j] = fmaf(a, sw[k * 44 + c0 + j], acc[j]);
    }
    int row = m0 + r;
    if (row < N_NODES) {
        float s = ns[row];
        #pragma unroll
        for (int j = 0; j < 11; j++) {
            int c = c0 + j;
            if (c < N_CLS) y2[(long)row * Y2_STRIDE + c] = acc[j] * s;
        }
    }
}

// ---------------- SpMM2 + epilogue: out = A@y2 * nd + b2 ----------------
__global__ __launch_bounds__(256) void k_spmm2(const float* __restrict__ y2,
                                               const int* __restrict__ row_ptr,
                                               const int* __restrict__ deg_in,
                                               const int* __restrict__ csr_src,
                                               const float* __restrict__ nd,
                                               const float* __restrict__ b2,
                                               float* __restrict__ out) {
    int wave = threadIdx.x >> 6, lane = threadIdx.x & 63;
    int n = blockIdx.x * 4 + wave;
    if (n >= N_NODES) return;
    if (lane >= N_CLS) return;
    int base = row_ptr[n], deg = deg_in[n];
    float a[8];
    #pragma unroll
    for (int u = 0; u < 8; ++u) a[u] = 0.f;
    int j = 0;
    for (; j + 8 <= deg; j += 8) {
        int s[8];
        #pragma unroll
        for (int u = 0; u < 8; ++u) s[u] = csr_src[base + j + u];
        #pragma unroll
        for (int u = 0; u < 8; ++u) a[u] += y2[(long)s[u] * Y2_STRIDE + lane];
    }
    for (; j < deg; ++j) {
        int s = csr_src[base + j];
        a[0] += y2[(long)s * Y2_STRIDE + lane];
    }
    float t = ((a[0] + a[1]) + (a[2] + a[3])) + ((a[4] + a[5]) + (a[6] + a[7]));
    out[(long)n * N_CLS + lane] = t * nd[n] + b2[lane];
}

extern "C" void kernel_launch(void* const* d_in, const int* in_sizes, int n_in,
                              void* d_out, int out_size, void* d_ws, size_t ws_size,
                              hipStream_t stream) {
    const float* x    = (const float*)d_in[0];
    const int*   esrc = (const int*)d_in[1];
    const int*   edst = (const int*)d_in[2];
    const float* W1   = (const float*)d_in[3];
    const float* b1   = (const float*)d_in[4];
    const float* W2   = (const float*)d_in[5];
    const float* b2   = (const float*)d_in[6];
    float* out = (float*)d_out;

    char* p = (char*)d_ws;
    auto alloc = [&](size_t bytes) {
        char* r = p;
        p += (bytes + 255) & ~(size_t)255;
        return r;
    };
    int*   deg_out = (int*)alloc((size_t)N_NODES * 4);
    int*   deg_in  = (int*)alloc((size_t)N_NODES * 4);
    float* ns      = (float*)alloc((size_t)N_NODES * 4);
    float* nd      = (float*)alloc((size_t)N_NODES * 4);
    int*   row_ptr = (int*)alloc((size_t)N_NODES * 4);
    int*   cursor  = (int*)alloc((size_t)N_NODES * 4);
    int*   blk     = (int*)alloc(1024 * 4);
    unsigned short* Bpk_hi = (unsigned short*)alloc((size_t)HIDDEN * KPAD * 2);
    unsigned short* Bpk_lo = (unsigned short*)alloc((size_t)HIDDEN * KPAD * 2);
    int*   csr     = (int*)alloc((size_t)N_EDGES * 4);
    float* y1      = (float*)alloc((size_t)N_NODES * HIDDEN * 4);  // reused as y2 (stride 48 fits)
    float* h1      = (float*)alloc((size_t)N_NODES * HIDDEN * 4);
    float* y2      = y1;
    if ((size_t)(p - (char*)d_ws) > ws_size) return;

    hipMemsetAsync(deg_out, 0, (size_t)N_NODES * 4, stream);
    hipMemsetAsync(deg_in,  0, (size_t)N_NODES * 4, stream);

    const int EB = (N_EDGES + 255) / 256;
    const int NB = (N_NODES + 255) / 256;
    const int SB = (N_NODES + 1023) / 1024;
    const int MB = (N_NODES + 127) / 128;

    k_deg<<<EB, 256, 0, stream>>>(esrc, edst, deg_out, deg_in);
    k_norm<<<NB, 256, 0, stream>>>(deg_out, deg_in, ns, nd);
    k_wconv<<<HIDDEN, 640, 0, stream>>>(W1, Bpk_hi, Bpk_lo);
    k_scan1<<<SB, 1024, 0, stream>>>(deg_in, row_ptr, blk);
    k_scan2<<<1, 128, 0, stream>>>(blk, SB);
    k_scan3<<<NB, 256, 0, stream>>>(row_ptr, blk, cursor);
    k_fill<<<EB, 256, 0, stream>>>(esrc, edst, cursor, csr);
    k_gemm1<<<MB, 256, 0, stream>>>(x, Bpk_hi, Bpk_lo, ns, y1);
    k_spmm1<<<(N_NODES + 3) / 4, 256, 0, stream>>>(y1, row_ptr, deg_in, csr, nd, b1, h1);
    k_gemm2<<<(N_NODES + 63) / 64, 256, 0, stream>>>(h1, W2, ns, y2);
    k_spmm2<<<(N_NODES + 3) / 4, 256, 0, stream>>>(y2, row_ptr, deg_in, csr, nd, b2, out);
}

// Round 4
// 901.808 us; speedup vs baseline: 1.0413x; 1.0413x over previous
//
#include <hip/hip_runtime.h>

#define N_NODES 100000
#define N_EDGES 1600000
#define N_FEAT  602
#define HIDDEN  128
#define N_CLS   41
#define Y2_STRIDE 48   // padded rows: 192B, cache-line aligned

typedef __attribute__((ext_vector_type(8))) short bf16x8;
typedef __attribute__((ext_vector_type(4))) float f32x4;

#define KPAD 608      // 19 * 32

typedef const __attribute__((address_space(1))) void gv_t;
typedef __attribute__((address_space(3))) void lv_t;

// bf16 round-to-nearest-even, returns hi and residual
__device__ inline unsigned short bf_hi(float f, float& rem) {
    unsigned int u = __float_as_uint(f);
    unsigned int r = u + 0x7FFF + ((u >> 16) & 1);
    unsigned short h = (unsigned short)(r >> 16);
    rem = f - __uint_as_float((unsigned int)h << 16);
    return h;
}
__device__ inline unsigned short bf_rn(float f) {
    unsigned int u = __float_as_uint(f);
    unsigned int r = u + 0x7FFF + ((u >> 16) & 1);
    return (unsigned short)(r >> 16);
}

// ---------------- degrees ----------------
__global__ void k_deg(const int* __restrict__ src, const int* __restrict__ dst,
                      int* __restrict__ deg_out, int* __restrict__ deg_in) {
    int e = blockIdx.x * blockDim.x + threadIdx.x;
    if (e < N_EDGES) {
        atomicAdd(&deg_out[src[e]], 1);
        atomicAdd(&deg_in[dst[e]], 1);
    }
}

__global__ void k_norm(const int* __restrict__ deg_out, const int* __restrict__ deg_in,
                       float* __restrict__ ns, float* __restrict__ nd) {
    int i = blockIdx.x * blockDim.x + threadIdx.x;
    if (i < N_NODES) {
        ns[i] = 1.0f / sqrtf((float)max(deg_out[i], 1));
        nd[i] = 1.0f / sqrtf((float)max(deg_in[i], 1));
    }
}

// ---------------- W1 convert: fp32 [602][128] -> bf16 hi/lo, staging-order + bank-swizzle ----
// Layout: Bpk[kt*4096 + col*32 + slot*8 + e] = W1^T[col][k = kt*32 + ch*8 + e],
// where slot = (ch + ((col>>1)&3)) & 3.  Staging (global_load_lds) copies this linearly
// into LDS[col*32 + ...]; the read side applies the same swizzle -> conflict-free b128.
__global__ void k_wconv(const float* __restrict__ W1,
                        unsigned short* __restrict__ Bpk_hi,
                        unsigned short* __restrict__ Bpk_lo) {
    int c = blockIdx.x;     // col 0..127
    int k = threadIdx.x;    // 0..639
    if (k >= KPAD) return;
    float w = (k < N_FEAT) ? W1[(long)k * HIDDEN + c] : 0.f;
    float rem;
    unsigned short h = bf_hi(w, rem);
    unsigned short l = bf_rn(rem);
    int kt = k >> 5;
    int ch = (k >> 3) & 3;
    int e  = k & 7;
    int slot = (ch + ((c >> 1) & 3)) & 3;
    long idx = (long)kt * 4096 + (long)c * 32 + slot * 8 + e;
    Bpk_hi[idx] = h;
    Bpk_lo[idx] = l;
}

// ---------------- exclusive scan of deg_in -> row_ptr ----------------
__global__ void k_scan1(const int* __restrict__ deg_in, int* __restrict__ row_ptr,
                        int* __restrict__ blk) {
    __shared__ int s[1024];
    int t = threadIdx.x;
    int i = blockIdx.x * 1024 + t;
    int v = (i < N_NODES) ? deg_in[i] : 0;
    s[t] = v; __syncthreads();
    for (int off = 1; off < 1024; off <<= 1) {
        int x = s[t];
        if (t >= off) x += s[t - off];
        __syncthreads();
        s[t] = x; __syncthreads();
    }
    if (i < N_NODES) row_ptr[i] = s[t] - v;
    if (t == 1023) blk[blockIdx.x] = s[1023];
}

__global__ void k_scan2(int* __restrict__ blk, int nblk) {
    __shared__ int s[128];
    int t = threadIdx.x;
    int v = (t < nblk) ? blk[t] : 0;
    s[t] = v; __syncthreads();
    for (int off = 1; off < 128; off <<= 1) {
        int x = s[t];
        if (t >= off) x += s[t - off];
        __syncthreads();
        s[t] = x; __syncthreads();
    }
    if (t < nblk) blk[t] = s[t] - v;
}

// also initializes cursor = row_ptr so k_fill needs no row_ptr gather
__global__ void k_scan3(int* __restrict__ row_ptr, const int* __restrict__ blk,
                        int* __restrict__ cursor) {
    int i = blockIdx.x * blockDim.x + threadIdx.x;
    if (i < N_NODES) {
        int v = row_ptr[i] + blk[i >> 10];
        row_ptr[i] = v;
        cursor[i] = v;
    }
}

// ---------------- CSR fill (bucket by dst); cursor pre-seeded with row_ptr ----------------
__global__ void k_fill(const int* __restrict__ src, const int* __restrict__ dst,
                       int* __restrict__ cursor, int* __restrict__ csr_src) {
    int e = blockIdx.x * blockDim.x + threadIdx.x;
    if (e < N_EDGES) {
        int p = atomicAdd(&cursor[dst[e]], 1);
        csr_src[p] = src[e];
    }
}

// ---------------- GEMM1 (split-bf16 MFMA, counted-vmcnt pipeline) ----------------
// y1 = ns ⊙ (x @ W1). 4 waves, wave owns 32 rows x 128 cols (acc 2x8 of 16x16).
// A: global -> regs as MFMA fragments, 1 tile ahead; B: bf16 hi/lo prepacked+swizzled,
// double-buffered LDS via global_load_lds.  Per-iter VMEM order is PINNED:
// [stage B(kt+1) (4)] fence [load A(kt+1) (8)] ... s_waitcnt vmcnt(8) + s_barrier
// -> the barrier wait drains ONLY the staging; the A-prefetch stays in flight
// (in-order vmcnt completion).  No vmcnt(0) anywhere in the main loop.
__global__ __launch_bounds__(256, 3) void k_gemm1(const float* __restrict__ x,
                                                  const unsigned short* __restrict__ Bpk_hi,
                                                  const unsigned short* __restrict__ Bpk_lo,
                                                  const float* __restrict__ ns,
                                                  float* __restrict__ y1) {
    __shared__ __align__(16) unsigned short Bh[2][128 * 32];   // 16 KB
    __shared__ __align__(16) unsigned short Bl[2][128 * 32];   // 16 KB

    int tid = threadIdx.x;
    int lane = tid & 63;
    int wave = tid >> 6;
    int quad = lane >> 4, l16 = lane & 15;
    int m0 = blockIdx.x * 128;

    f32x4 acc[2][8];
    #pragma unroll
    for (int i = 0; i < 2; i++)
        #pragma unroll
        for (int j = 0; j < 8; j++)
            acc[i][j] = (f32x4){0.f, 0.f, 0.f, 0.f};

    // A fragment rows for this lane (mi = 0,1), clamped for the last block
    long r0 = min(m0 + wave * 32 + l16,      N_NODES - 1);
    long r1 = min(m0 + wave * 32 + 16 + l16, N_NODES - 1);
    const float* xr0 = x + r0 * N_FEAT + quad * 8;
    const float* xr1 = x + r1 * N_FEAT + quad * 8;

    // B staging: instr i, lane l -> col = wave*32 + i*16 + l/4, 16B chunk = l%4 (linear copy)
    int b_col = wave * 32 + (lane >> 2);
    int b_chn = lane & 3;
    // B read swizzle slot (shorts): logical chunk 'quad' of col bc lives at
    // slot (quad + ((bc>>1)&3))&3; since bc = ni*16 + l16, (bc>>1)&3 = (l16>>1)&3.
    int sl8 = ((quad + ((l16 >> 1) & 3)) & 3) * 8;

    auto stageB = [&](int kt, int buf) {
        #pragma unroll
        for (int i = 0; i < 2; ++i) {
            int col = b_col + i * 16;
            long g = (long)kt * 4096 + (long)col * 32 + b_chn * 8;
            __builtin_amdgcn_global_load_lds((gv_t*)(Bpk_hi + g), (lv_t*)&Bh[buf][wave * 1024 + i * 512], 16, 0, 0);
            __builtin_amdgcn_global_load_lds((gv_t*)(Bpk_lo + g), (lv_t*)&Bl[buf][wave * 1024 + i * 512], 16, 0, 0);
        }
    };

    float4 c0, c1, c2, c3;   // A regs for tile kt
    float4 n0, n1, n2, n3;   // A regs for tile kt+1 (in flight)

    // ---- prologue: stage B(0), then load A(0); drain ONLY the staging ----
    stageB(0, 0);
    asm volatile("" ::: "memory");     // pin issue order: staging before A-loads
    c0 = *(const float4*)(xr0);      c1 = *(const float4*)(xr0 + 4);
    c2 = *(const float4*)(xr1);      c3 = *(const float4*)(xr1 + 4);
    asm volatile("s_waitcnt vmcnt(8)" ::: "memory");
    __builtin_amdgcn_s_barrier();

    for (int kt = 0; kt < 19; ++kt) {
        int cur = kt & 1;

        // ---- issue next tile's staging FIRST, then A-prefetch (order pinned) ----
        if (kt < 18) {
            stageB(kt + 1, cur ^ 1);
            asm volatile("" ::: "memory");
            const float* p0 = xr0 + (kt + 1) * 32;
            const float* p1 = xr1 + (kt + 1) * 32;
            n0 = *(const float4*)(p0);     n1 = *(const float4*)(p0 + 4);
            n2 = *(const float4*)(p1);     n3 = *(const float4*)(p1 + 4);
        }

        // ---- convert current A regs -> bf16 hi/lo fragments (in-register) ----
        if (kt == 18 && quad == 3) {
            // tile covers k = 576..607; zero k >= 602 (quad 3 holds k 600..607)
            c0.z = 0.f; c0.w = 0.f; c1 = make_float4(0.f, 0.f, 0.f, 0.f);
            c2.z = 0.f; c2.w = 0.f; c3 = make_float4(0.f, 0.f, 0.f, 0.f);
        }
        bf16x8 ah[2], al[2];
        {
            float rem;
            ah[0][0] = (short)bf_hi(c0.x, rem); al[0][0] = (short)bf_rn(rem);
            ah[0][1] = (short)bf_hi(c0.y, rem); al[0][1] = (short)bf_rn(rem);
            ah[0][2] = (short)bf_hi(c0.z, rem); al[0][2] = (short)bf_rn(rem);
            ah[0][3] = (short)bf_hi(c0.w, rem); al[0][3] = (short)bf_rn(rem);
            ah[0][4] = (short)bf_hi(c1.x, rem); al[0][4] = (short)bf_rn(rem);
            ah[0][5] = (short)bf_hi(c1.y, rem); al[0][5] = (short)bf_rn(rem);
            ah[0][6] = (short)bf_hi(c1.z, rem); al[0][6] = (short)bf_rn(rem);
            ah[0][7] = (short)bf_hi(c1.w, rem); al[0][7] = (short)bf_rn(rem);
            ah[1][0] = (short)bf_hi(c2.x, rem); al[1][0] = (short)bf_rn(rem);
            ah[1][1] = (short)bf_hi(c2.y, rem); al[1][1] = (short)bf_rn(rem);
            ah[1][2] = (short)bf_hi(c2.z, rem); al[1][2] = (short)bf_rn(rem);
            ah[1][3] = (short)bf_hi(c2.w, rem); al[1][3] = (short)bf_rn(rem);
            ah[1][4] = (short)bf_hi(c3.x, rem); al[1][4] = (short)bf_rn(rem);
            ah[1][5] = (short)bf_hi(c3.y, rem); al[1][5] = (short)bf_rn(rem);
            ah[1][6] = (short)bf_hi(c3.z, rem); al[1][6] = (short)bf_rn(rem);
            ah[1][7] = (short)bf_hi(c3.w, rem); al[1][7] = (short)bf_rn(rem);
        }

        // ---- B fragments from LDS (swizzled, conflict-free) + MFMA ----
        #pragma unroll
        for (int ni = 0; ni < 8; ++ni) {
            int bc = ni * 16 + l16;
            bf16x8 vh = *(bf16x8*)&Bh[cur][bc * 32 + sl8];
            bf16x8 vl = *(bf16x8*)&Bl[cur][bc * 32 + sl8];
            #pragma unroll
            for (int mi = 0; mi < 2; ++mi) {
                acc[mi][ni] = __builtin_amdgcn_mfma_f32_16x16x32_bf16(ah[mi], vh, acc[mi][ni], 0, 0, 0);
                acc[mi][ni] = __builtin_amdgcn_mfma_f32_16x16x32_bf16(al[mi], vh, acc[mi][ni], 0, 0, 0);
                acc[mi][ni] = __builtin_amdgcn_mfma_f32_16x16x32_bf16(ah[mi], vl, acc[mi][ni], 0, 0, 0);
            }
        }

        if (kt < 18) {
            // drain ONLY the 4 staging loads (oldest); 8 A-prefetch loads stay in flight
            asm volatile("s_waitcnt vmcnt(8)" ::: "memory");
            __builtin_amdgcn_s_barrier();
            c0 = n0; c1 = n1; c2 = n2; c3 = n3;
        }
    }

    // epilogue: C/D layout col = lane&15, row = quad*4 + r
    #pragma unroll
    for (int mi = 0; mi < 2; ++mi) {
        #pragma unroll
        for (int r = 0; r < 4; ++r) {
            int row = m0 + wave * 32 + mi * 16 + quad * 4 + r;
            if (row < N_NODES) {
                float s = ns[row];
                #pragma unroll
                for (int ni = 0; ni < 8; ++ni) {
                    int col = ni * 16 + l16;
                    y1[(long)row * HIDDEN + col] = acc[mi][ni][r] * s;
                }
            }
        }
    }
}

// ---------------- SpMM1 + epilogue: h1 = relu(A@y1 * nd + b1) ----------------
// Lane-paired gathers: 32 lanes cover one y1 row as float4; half = lane>>5 selects
// edge j+half -> 4 paired loads per iter = 16 edges in flight per wave.
__global__ __launch_bounds__(256) void k_spmm1(const float* __restrict__ y1,
                                               const int* __restrict__ row_ptr,
                                               const int* __restrict__ deg_in,
                                               const int* __restrict__ csr_src,
                                               const float* __restrict__ nd,
                                               const float* __restrict__ b1,
                                               float* __restrict__ h1) {
    int wave = threadIdx.x >> 6, lane = threadIdx.x & 63;
    int n = blockIdx.x * 4 + wave;
    if (n >= N_NODES) return;
    int base = row_ptr[n], deg = deg_in[n];
    int half = lane >> 5;
    int c4 = (lane & 31) << 2;      // feature start: 0,4,...,124
    f32x4 a[4];
    #pragma unroll
    for (int u = 0; u < 4; ++u) a[u] = (f32x4){0.f, 0.f, 0.f, 0.f};
    int j = 0;
    for (; j + 8 <= deg; j += 8) {
        int s[4];
        #pragma unroll
        for (int u = 0; u < 4; ++u) s[u] = csr_src[base + j + 2 * u + half];
        #pragma unroll
        for (int u = 0; u < 4; ++u)
            a[u] += *(const f32x4*)(y1 + (long)s[u] * HIDDEN + c4);
    }
    for (; j + 2 <= deg; j += 2) {
        int s = csr_src[base + j + half];
        a[0] += *(const f32x4*)(y1 + (long)s * HIDDEN + c4);
    }
    if (j < deg && half == 0) {
        int s = csr_src[base + j];
        a[1] += *(const f32x4*)(y1 + (long)s * HIDDEN + c4);
    }
    f32x4 t = (a[0] + a[1]) + (a[2] + a[3]);
    #pragma unroll
    for (int i = 0; i < 4; ++i) t[i] += __shfl_xor(t[i], 32, 64);
    if (half == 0) {
        float d = nd[n];
        f32x4 b = *(const f32x4*)(b1 + c4);
        f32x4 r;
        #pragma unroll
        for (int i = 0; i < 4; ++i) r[i] = fmaxf(t[i] * d + b[i], 0.f);
        *(f32x4*)(h1 + (long)n * HIDDEN + c4) = r;
    }
}

// ---------------- GEMM2: y2 = ns ⊙ (h1 @ W2), padded rows (stride 48) ----------------
__global__ __launch_bounds__(256) void k_gemm2(const float* __restrict__ h1,
                                               const float* __restrict__ W2,
                                               const float* __restrict__ ns,
                                               float* __restrict__ y2) {
    __shared__ float sz[64 * 132];
    __shared__ float sw[128 * 44];
    int tid = threadIdx.x;
    int m0 = blockIdx.x * 64;
    for (int idx = tid; idx < 128 * 44; idx += 256) {
        int k = idx / 44, c = idx % 44;
        sw[idx] = (c < N_CLS) ? W2[k * N_CLS + c] : 0.f;
    }
    for (int idx = tid; idx < 64 * 32; idx += 256) {
        int r = idx >> 5, q = idx & 31;
        int row = m0 + r;
        float4 v = make_float4(0.f, 0.f, 0.f, 0.f);
        if (row < N_NODES) v = ((const float4*)h1)[(long)row * 32 + q];
        *((float4*)&sz[r * 132 + q * 4]) = v;
    }
    __syncthreads();
    int r = tid >> 2, cq = tid & 3;
    int c0 = cq * 11;
    float acc[11];
    #pragma unroll
    for (int j = 0; j < 11; j++) acc[j] = 0.f;
    #pragma unroll 8
    for (int k = 0; k < 128; ++k) {
        float a = sz[r * 132 + k];
        #pragma unroll
        for (int j = 0; j < 11; j++) acc[j] = fmaf(a, sw[k * 44 + c0 + j], acc[j]);
    }
    int row = m0 + r;
    if (row < N_NODES) {
        float s = ns[row];
        #pragma unroll
        for (int j = 0; j < 11; j++) {
            int c = c0 + j;
            if (c < N_CLS) y2[(long)row * Y2_STRIDE + c] = acc[j] * s;
        }
    }
}

// ---------------- SpMM2 + epilogue: out = A@y2 * nd + b2 ----------------
__global__ __launch_bounds__(256) void k_spmm2(const float* __restrict__ y2,
                                               const int* __restrict__ row_ptr,
                                               const int* __restrict__ deg_in,
                                               const int* __restrict__ csr_src,
                                               const float* __restrict__ nd,
                                               const float* __restrict__ b2,
                                               float* __restrict__ out) {
    int wave = threadIdx.x >> 6, lane = threadIdx.x & 63;
    int n = blockIdx.x * 4 + wave;
    if (n >= N_NODES) return;
    if (lane >= N_CLS) return;
    int base = row_ptr[n], deg = deg_in[n];
    float a[8];
    #pragma unroll
    for (int u = 0; u < 8; ++u) a[u] = 0.f;
    int j = 0;
    for (; j + 8 <= deg; j += 8) {
        int s[8];
        #pragma unroll
        for (int u = 0; u < 8; ++u) s[u] = csr_src[base + j + u];
        #pragma unroll
        for (int u = 0; u < 8; ++u) a[u] += y2[(long)s[u] * Y2_STRIDE + lane];
    }
    for (; j < deg; ++j) {
        int s = csr_src[base + j];
        a[0] += y2[(long)s * Y2_STRIDE + lane];
    }
    float t = ((a[0] + a[1]) + (a[2] + a[3])) + ((a[4] + a[5]) + (a[6] + a[7]));
    out[(long)n * N_CLS + lane] = t * nd[n] + b2[lane];
}

extern "C" void kernel_launch(void* const* d_in, const int* in_sizes, int n_in,
                              void* d_out, int out_size, void* d_ws, size_t ws_size,
                              hipStream_t stream) {
    const float* x    = (const float*)d_in[0];
    const int*   esrc = (const int*)d_in[1];
    const int*   edst = (const int*)d_in[2];
    const float* W1   = (const float*)d_in[3];
    const float* b1   = (const float*)d_in[4];
    const float* W2   = (const float*)d_in[5];
    const float* b2   = (const float*)d_in[6];
    float* out = (float*)d_out;

    char* p = (char*)d_ws;
    auto alloc = [&](size_t bytes) {
        char* r = p;
        p += (bytes + 255) & ~(size_t)255;
        return r;
    };
    int*   deg_out = (int*)alloc((size_t)N_NODES * 4);
    int*   deg_in  = (int*)alloc((size_t)N_NODES * 4);
    float* ns      = (float*)alloc((size_t)N_NODES * 4);
    float* nd      = (float*)alloc((size_t)N_NODES * 4);
    int*   row_ptr = (int*)alloc((size_t)N_NODES * 4);
    int*   cursor  = (int*)alloc((size_t)N_NODES * 4);
    int*   blk     = (int*)alloc(1024 * 4);
    unsigned short* Bpk_hi = (unsigned short*)alloc((size_t)HIDDEN * KPAD * 2);
    unsigned short* Bpk_lo = (unsigned short*)alloc((size_t)HIDDEN * KPAD * 2);
    int*   csr     = (int*)alloc((size_t)N_EDGES * 4);
    float* y1      = (float*)alloc((size_t)N_NODES * HIDDEN * 4);  // reused as y2 (stride 48 fits)
    float* h1      = (float*)alloc((size_t)N_NODES * HIDDEN * 4);
    float* y2      = y1;
    if ((size_t)(p - (char*)d_ws) > ws_size) return;

    hipMemsetAsync(deg_out, 0, (size_t)N_NODES * 4, stream);
    hipMemsetAsync(deg_in,  0, (size_t)N_NODES * 4, stream);

    const int EB = (N_EDGES + 255) / 256;
    const int NB = (N_NODES + 255) / 256;
    const int SB = (N_NODES + 1023) / 1024;
    const int MB = (N_NODES + 127) / 128;

    k_deg<<<EB, 256, 0, stream>>>(esrc, edst, deg_out, deg_in);
    k_norm<<<NB, 256, 0, stream>>>(deg_out, deg_in, ns, nd);
    k_wconv<<<HIDDEN, 640, 0, stream>>>(W1, Bpk_hi, Bpk_lo);
    k_scan1<<<SB, 1024, 0, stream>>>(deg_in, row_ptr, blk);
    k_scan2<<<1, 128, 0, stream>>>(blk, SB);
    k_scan3<<<NB, 256, 0, stream>>>(row_ptr, blk, cursor);
    k_fill<<<EB, 256, 0, stream>>>(esrc, edst, cursor, csr);
    k_gemm1<<<MB, 256, 0, stream>>>(x, Bpk_hi, Bpk_lo, ns, y1);
    k_spmm1<<<(N_NODES + 3) / 4, 256, 0, stream>>>(y1, row_ptr, deg_in, csr, nd, b1, h1);
    k_gemm2<<<(N_NODES + 63) / 64, 256, 0, stream>>>(h1, W2, ns, y2);
    k_spmm2<<<(N_NODES + 3) / 4, 256, 0, stream>>>(y2, row_ptr, deg_in, csr, nd, b2, out);
}